// Round 2
// baseline (684.354 us; speedup 1.0000x reference)
//
#include <hip/hip_runtime.h>

#define T_STEPS 200
#define BATCH 256
#define D_IN 256
#define H1N 512
#define H2N 512
#define D_LAT 128
#define MROWS (T_STEPS * BATCH)   /* 51200 */
#define BHE (BATCH * H1N)         /* 131072 elements per timestep slab */

#define BM 128
#define BN 128
#define BK 32
#define PADF 4

// C[M,N] = A[M,K] * B[N,K]^T + bias[N]; A is f32 or u8 (binary spikes)
template <bool A_U8>
__global__ __launch_bounds__(256, 2) void gemm_nt(const void* __restrict__ Av,
                                                  const float* __restrict__ B,
                                                  const float* __restrict__ bias,
                                                  float* __restrict__ C,
                                                  int M, int N, int K) {
    __shared__ float As[BK][BM + PADF];
    __shared__ float Bs[BK][BN + PADF];

    const int tid = threadIdx.x;
    const int m0 = blockIdx.x * BM;
    const int n0 = blockIdx.y * BN;
    const int tx = tid & 15;
    const int ty = tid >> 4;

    const int lrow = tid >> 1;        // 0..127 (row within tile)
    const int lcol = (tid & 1) * 16;  // 0 or 16 (start col within BK)

    float acc[8][8];
#pragma unroll
    for (int i = 0; i < 8; ++i)
#pragma unroll
        for (int j = 0; j < 8; ++j) acc[i][j] = 0.f;

    for (int k0 = 0; k0 < K; k0 += BK) {
        // ---- stage A tile (128 rows x 32 k) transposed into As[k][m]
        if constexpr (A_U8) {
            const unsigned char* A = (const unsigned char*)Av;
            union { uint4 u; unsigned char c[16]; } v;
            v.u = *reinterpret_cast<const uint4*>(&A[(size_t)(m0 + lrow) * K + k0 + lcol]);
#pragma unroll
            for (int c = 0; c < 16; ++c) As[lcol + c][lrow] = (float)v.c[c];
        } else {
            const float* A = (const float*)Av;
#pragma unroll
            for (int q = 0; q < 4; ++q) {
                float4 v = *reinterpret_cast<const float4*>(
                    &A[(size_t)(m0 + lrow) * K + k0 + lcol + q * 4]);
                As[lcol + q * 4 + 0][lrow] = v.x;
                As[lcol + q * 4 + 1][lrow] = v.y;
                As[lcol + q * 4 + 2][lrow] = v.z;
                As[lcol + q * 4 + 3][lrow] = v.w;
            }
        }
        // ---- stage B tile (128 n-rows x 32 k) transposed into Bs[k][n]
#pragma unroll
        for (int q = 0; q < 4; ++q) {
            float4 v = *reinterpret_cast<const float4*>(
                &B[(size_t)(n0 + lrow) * K + k0 + lcol + q * 4]);
            Bs[lcol + q * 4 + 0][lrow] = v.x;
            Bs[lcol + q * 4 + 1][lrow] = v.y;
            Bs[lcol + q * 4 + 2][lrow] = v.z;
            Bs[lcol + q * 4 + 3][lrow] = v.w;
        }
        __syncthreads();

#pragma unroll
        for (int kk = 0; kk < BK; ++kk) {
            float4 a0 = *reinterpret_cast<const float4*>(&As[kk][ty * 8]);
            float4 a1 = *reinterpret_cast<const float4*>(&As[kk][ty * 8 + 4]);
            float4 b0 = *reinterpret_cast<const float4*>(&Bs[kk][tx * 8]);
            float4 b1 = *reinterpret_cast<const float4*>(&Bs[kk][tx * 8 + 4]);
            float a[8] = {a0.x, a0.y, a0.z, a0.w, a1.x, a1.y, a1.z, a1.w};
            float b[8] = {b0.x, b0.y, b0.z, b0.w, b1.x, b1.y, b1.z, b1.w};
#pragma unroll
            for (int i = 0; i < 8; ++i)
#pragma unroll
                for (int j = 0; j < 8; ++j) acc[i][j] = fmaf(a[i], b[j], acc[i][j]);
        }
        __syncthreads();
    }

    float bv[8];
#pragma unroll
    for (int j = 0; j < 8; ++j) bv[j] = bias[n0 + tx * 8 + j];

#pragma unroll
    for (int i = 0; i < 8; ++i) {
        const int m = m0 + ty * 8 + i;
#pragma unroll
        for (int j = 0; j < 8; ++j) acc[i][j] += bv[j];
        float4* cp = reinterpret_cast<float4*>(&C[(size_t)m * N + n0 + tx * 8]);
        cp[0] = make_float4(acc[i][0], acc[i][1], acc[i][2], acc[i][3]);
        cp[1] = make_float4(acc[i][4], acc[i][5], acc[i][6], acc[i][7]);
    }
}

// Elementwise LIF recurrence over T for each (b, n):
//   r_t = (m_{t-1} > TH); m_t = beta*m_{t-1} + h_t - r_t*TH; s_t = (m_t - TH > 0)
__global__ __launch_bounds__(256) void lif_scan(const float* __restrict__ H,
                                                const float* __restrict__ beta_ptr,
                                                unsigned char* __restrict__ S,
                                                float* __restrict__ fr,
                                                unsigned char* __restrict__ s_last,
                                                int write_S, int write_last) {
    const int idx = blockIdx.x * blockDim.x + threadIdx.x;  // < BHE
    const float be = fminf(fmaxf(beta_ptr[0], 0.f), 1.f);
    float m = 0.f;
    float r = 0.f;
    int cnt = 0;
#pragma unroll 4
    for (int t = 0; t < T_STEPS; ++t) {
        const float h = H[(size_t)t * BHE + idx];
        m = be * m + h - r;  // r in {0,1}, TH = 1
        const bool sp = m > 1.0f;
        r = sp ? 1.0f : 0.0f;
        cnt += sp ? 1 : 0;
        if (write_S) S[(size_t)t * BHE + idx] = sp ? (unsigned char)1 : (unsigned char)0;
    }
    fr[idx] = (float)cnt / (float)T_STEPS;
    if (write_last) s_last[idx] = (r > 0.5f) ? (unsigned char)1 : (unsigned char)0;
}

// latent = LN(s_last @ Wout^T + bout) * gamma + beta ; one block per batch row
__global__ __launch_bounds__(128) void latent_ln(const unsigned char* __restrict__ s_last,
                                                 const float* __restrict__ Wout,
                                                 const float* __restrict__ bout,
                                                 const float* __restrict__ gamma,
                                                 const float* __restrict__ lbeta,
                                                 float* __restrict__ out) {
    const int b = blockIdx.x;
    const int d = threadIdx.x;  // 128 threads
    __shared__ float sv[H2N];
    for (int k = d; k < H2N; k += 128) sv[k] = (float)s_last[b * H2N + k];
    __syncthreads();

    float a = 0.f;
    const float* w = &Wout[(size_t)d * H2N];
#pragma unroll 8
    for (int k = 0; k < H2N; ++k) a = fmaf(sv[k], w[k], a);
    a += bout[d];

    __shared__ float red[128];
    red[d] = a;
    __syncthreads();
    for (int s = 64; s > 0; s >>= 1) {
        if (d < s) red[d] += red[d + s];
        __syncthreads();
    }
    const float mu = red[0] * (1.0f / 128.0f);
    __syncthreads();
    const float df = a - mu;
    red[d] = df * df;
    __syncthreads();
    for (int s = 64; s > 0; s >>= 1) {
        if (d < s) red[d] += red[d + s];
        __syncthreads();
    }
    const float var = red[0] * (1.0f / 128.0f);
    const float y = df * (1.0f / sqrtf(var + 1e-5f)) * gamma[d] + lbeta[d];
    out[(size_t)b * D_LAT + d] = y;
}

extern "C" void kernel_launch(void* const* d_in, const int* in_sizes, int n_in,
                              void* d_out, int out_size, void* d_ws, size_t ws_size,
                              hipStream_t stream) {
    const float* X     = (const float*)d_in[0];   // [T,B,D_IN]
    const float* W1    = (const float*)d_in[1];   // [H1,D_IN]
    const float* b1    = (const float*)d_in[2];
    const float* beta0 = (const float*)d_in[3];
    const float* W2    = (const float*)d_in[4];   // [H2,H1]
    const float* b2    = (const float*)d_in[5];
    const float* beta1 = (const float*)d_in[6];
    const float* Wout  = (const float*)d_in[7];   // [D_LAT,H2]
    const float* bout  = (const float*)d_in[8];
    const float* lng   = (const float*)d_in[9];
    const float* lnb   = (const float*)d_in[10];

    float* out    = (float*)d_out;
    float* latent = out;                          // [B, D_LAT]
    float* fr0    = out + BATCH * D_LAT;          // [B, H1]
    float* fr1    = fr0 + BATCH * H1N;            // [B, H2]

    char* ws = (char*)d_ws;
    float* Hbuf = (float*)ws;                                        // [51200,512] f32 (reused for H1all then H2all)
    unsigned char* S0 = (unsigned char*)(ws + (size_t)MROWS * H1N * 4);  // [51200,512] u8
    unsigned char* s1last = S0 + (size_t)MROWS * H1N;                    // [B,H2] u8

    // 1) H1all = X @ W1^T + b1
    gemm_nt<false><<<dim3(MROWS / BM, H1N / BN), 256, 0, stream>>>(
        (const void*)X, W1, b1, Hbuf, MROWS, H1N, D_IN);
    // 2) layer-0 LIF scan -> S0 (u8), fr0
    lif_scan<<<dim3(BHE / 256), 256, 0, stream>>>(Hbuf, beta0, S0, fr0, nullptr, 1, 0);
    // 3) H2all = S0 @ W2^T + b2  (overwrites Hbuf)
    gemm_nt<true><<<dim3(MROWS / BM, H2N / BN), 256, 0, stream>>>(
        (const void*)S0, W2, b2, Hbuf, MROWS, H2N, H1N);
    // 4) layer-1 LIF scan -> fr1, s1_last
    lif_scan<<<dim3(BHE / 256), 256, 0, stream>>>(Hbuf, beta1, nullptr, fr1, s1last, 0, 1);
    // 5) latent + LayerNorm
    latent_ln<<<dim3(BATCH), 128, 0, stream>>>(s1last, Wout, bout, lng, lnb, latent);
}

// Round 3
// 406.292 us; speedup vs baseline: 1.6844x; 1.6844x over previous
//
#include <hip/hip_runtime.h>

typedef _Float16 half8 __attribute__((ext_vector_type(8)));
typedef _Float16 half4v __attribute__((ext_vector_type(4)));
typedef float f32x4 __attribute__((ext_vector_type(4)));

#define T_STEPS 200
#define BATCH 256
#define D_IN 256
#define H1N 512
#define H2N 512
#define D_LAT 128
#define BHE (BATCH * H1N)   /* 131072 */
#define TC 100              /* timesteps per chunk */
#define NCH 2
#define MC (TC * BATCH)     /* 25600 rows per chunk */

// ---------- fp16 2-term split: x = hi + 2^-11 * lo'  (lo' = (x-hi)*2048) ----------
__global__ __launch_bounds__(256) void split_kern(const float* __restrict__ in,
                                                  _Float16* __restrict__ hi,
                                                  _Float16* __restrict__ lo, int n4) {
    int i = blockIdx.x * 256 + threadIdx.x;
    if (i >= n4) return;
    float4 v = reinterpret_cast<const float4*>(in)[i];
    float vv[4] = {v.x, v.y, v.z, v.w};
    half4v h, l;
#pragma unroll
    for (int c = 0; c < 4; ++c) {
        _Float16 hh = (_Float16)vv[c];
        h[c] = hh;
        l[c] = (_Float16)((vv[c] - (float)hh) * 2048.0f);
    }
    reinterpret_cast<half4v*>(hi)[i] = h;
    reinterpret_cast<half4v*>(lo)[i] = l;
}

// ---------- MFMA GEMM: C[M,N] = A@B^T + bias, fp16-split operands, f32 out ----------
// A,B row-major [rows, K] fp16. ASPLIT: A has hi/lo (3 mfma); else A exact (2 mfma).
// acc layout (m89-verified): D col=lane&15, row=(lane>>4)*4+reg.
// LDS tiles [128][32] fp16, slot-swizzle: slot ^= (row>>1)&3  -> 2-way max (free).
template <bool ASPLIT>
__global__ __launch_bounds__(256, 2) void gemm_mfma(const _Float16* __restrict__ Ah,
                                                    const _Float16* __restrict__ Al,
                                                    const _Float16* __restrict__ Bh,
                                                    const _Float16* __restrict__ Bl,
                                                    const float* __restrict__ bias,
                                                    float* __restrict__ C,
                                                    int M, int N, int K) {
    __shared__ _Float16 sAh[128 * 32];
    __shared__ _Float16 sAl[128 * 32];
    __shared__ _Float16 sBh[128 * 32];
    __shared__ _Float16 sBl[128 * 32];

    const int tid = threadIdx.x;
    const int lane = tid & 63, wid = tid >> 6;
    const int wr = wid >> 1, wc = wid & 1;       // wave 2x2 grid, each 64x64
    const int m0 = blockIdx.x * 128, n0 = blockIdx.y * 128;
    const int frow = lane & 15, kb = lane >> 4;
    const int swf = (frow >> 1) & 3;

    const int srow = tid >> 2;  // staging row 0..63 (+64 for chunk 1)
    const int ls = tid & 3;     // logical k-slot (8 fp16 = 16B)

    f32x4 acc0[4][4] = {};
    f32x4 acc1[4][4] = {};

    for (int k0 = 0; k0 < K; k0 += 32) {
#pragma unroll
        for (int c = 0; c < 2; ++c) {
            const int row = c * 64 + srow;
            const int sw = (row >> 1) & 3;
            const int dst = row * 32 + 8 * (ls ^ sw);
            const size_t asrc = (size_t)(m0 + row) * K + k0 + 8 * ls;
            const size_t bsrc = (size_t)(n0 + row) * K + k0 + 8 * ls;
            *reinterpret_cast<uint4*>(&sAh[dst]) = *reinterpret_cast<const uint4*>(&Ah[asrc]);
            if constexpr (ASPLIT)
                *reinterpret_cast<uint4*>(&sAl[dst]) = *reinterpret_cast<const uint4*>(&Al[asrc]);
            *reinterpret_cast<uint4*>(&sBh[dst]) = *reinterpret_cast<const uint4*>(&Bh[bsrc]);
            *reinterpret_cast<uint4*>(&sBl[dst]) = *reinterpret_cast<const uint4*>(&Bl[bsrc]);
        }
        __syncthreads();

        half8 ah[4], al[4];
#pragma unroll
        for (int mi = 0; mi < 4; ++mi) {
            const int off = (wr * 64 + mi * 16 + frow) * 32 + 8 * (kb ^ swf);
            ah[mi] = *reinterpret_cast<const half8*>(&sAh[off]);
            if constexpr (ASPLIT) al[mi] = *reinterpret_cast<const half8*>(&sAl[off]);
        }
#pragma unroll
        for (int ni = 0; ni < 4; ++ni) {
            const int off = (wc * 64 + ni * 16 + frow) * 32 + 8 * (kb ^ swf);
            half8 bh = *reinterpret_cast<const half8*>(&sBh[off]);
            half8 bl = *reinterpret_cast<const half8*>(&sBl[off]);
#pragma unroll
            for (int mi = 0; mi < 4; ++mi) {
                acc0[mi][ni] = __builtin_amdgcn_mfma_f32_16x16x32_f16(ah[mi], bh, acc0[mi][ni], 0, 0, 0);
                acc1[mi][ni] = __builtin_amdgcn_mfma_f32_16x16x32_f16(ah[mi], bl, acc1[mi][ni], 0, 0, 0);
                if constexpr (ASPLIT)
                    acc1[mi][ni] = __builtin_amdgcn_mfma_f32_16x16x32_f16(al[mi], bh, acc1[mi][ni], 0, 0, 0);
            }
        }
        __syncthreads();
    }

#pragma unroll
    for (int mi = 0; mi < 4; ++mi) {
#pragma unroll
        for (int ni = 0; ni < 4; ++ni) {
            const int col = n0 + wc * 64 + ni * 16 + frow;
            const float bb = bias[col];
#pragma unroll
            for (int r = 0; r < 4; ++r) {
                const int m = m0 + wr * 64 + mi * 16 + kb * 4 + r;
                C[(size_t)m * N + col] =
                    acc0[mi][ni][r] + 4.8828125e-4f * acc1[mi][ni][r] + bb;
            }
        }
    }
}

// ---------- chunked LIF scan (carries m & spike-count across chunks) ----------
__global__ __launch_bounds__(256) void lif_scan_c(const float* __restrict__ H,
                                                  const float* __restrict__ beta_ptr,
                                                  _Float16* __restrict__ S,
                                                  float* __restrict__ m_state,
                                                  float* __restrict__ cnt_state,
                                                  float* __restrict__ fr_out,
                                                  unsigned char* __restrict__ s_last,
                                                  int first, int last, int writeS, int writeLast) {
    const int idx = blockIdx.x * 256 + threadIdx.x;  // < BHE
    const float be = fminf(fmaxf(beta_ptr[0], 0.f), 1.f);
    float m = first ? 0.f : m_state[idx];
    float cnt = first ? 0.f : cnt_state[idx];
    float r = (m > 1.0f) ? 1.f : 0.f;
#pragma unroll 4
    for (int t = 0; t < TC; ++t) {
        const float h = H[(size_t)t * BHE + idx];
        m = be * m + h - r;  // reset-by-subtraction, TH=1
        const bool sp = m > 1.0f;
        r = sp ? 1.f : 0.f;
        cnt += sp ? 1.f : 0.f;
        if (writeS) S[(size_t)t * BHE + idx] = sp ? (_Float16)1.f : (_Float16)0.f;
    }
    if (last) {
        fr_out[idx] = cnt / 200.0f;
        if (writeLast) s_last[idx] = (r > 0.5f) ? 1 : 0;
    } else {
        m_state[idx] = m;
        cnt_state[idx] = cnt;
    }
}

// ---------- latent = LN(s_last @ Wout^T + bout) ----------
__global__ __launch_bounds__(128) void latent_ln(const unsigned char* __restrict__ s_last,
                                                 const float* __restrict__ Wout,
                                                 const float* __restrict__ bout,
                                                 const float* __restrict__ gamma,
                                                 const float* __restrict__ lbeta,
                                                 float* __restrict__ out) {
    const int b = blockIdx.x;
    const int d = threadIdx.x;
    __shared__ float sv[H2N];
    for (int k = d; k < H2N; k += 128) sv[k] = (float)s_last[b * H2N + k];
    __syncthreads();

    float a = 0.f;
    const float* w = &Wout[(size_t)d * H2N];
#pragma unroll 8
    for (int k = 0; k < H2N; ++k) a = fmaf(sv[k], w[k], a);
    a += bout[d];

    __shared__ float red[128];
    red[d] = a;
    __syncthreads();
    for (int s = 64; s > 0; s >>= 1) {
        if (d < s) red[d] += red[d + s];
        __syncthreads();
    }
    const float mu = red[0] * (1.0f / 128.0f);
    __syncthreads();
    const float df = a - mu;
    red[d] = df * df;
    __syncthreads();
    for (int s = 64; s > 0; s >>= 1) {
        if (d < s) red[d] += red[d + s];
        __syncthreads();
    }
    const float var = red[0] * (1.0f / 128.0f);
    out[(size_t)b * D_LAT + d] = df * (1.0f / sqrtf(var + 1e-5f)) * gamma[d] + lbeta[d];
}

extern "C" void kernel_launch(void* const* d_in, const int* in_sizes, int n_in,
                              void* d_out, int out_size, void* d_ws, size_t ws_size,
                              hipStream_t stream) {
    const float* X     = (const float*)d_in[0];
    const float* W1    = (const float*)d_in[1];
    const float* b1    = (const float*)d_in[2];
    const float* beta0 = (const float*)d_in[3];
    const float* W2    = (const float*)d_in[4];
    const float* b2    = (const float*)d_in[5];
    const float* beta1 = (const float*)d_in[6];
    const float* Wout  = (const float*)d_in[7];
    const float* bout  = (const float*)d_in[8];
    const float* lng   = (const float*)d_in[9];
    const float* lnb   = (const float*)d_in[10];

    float* out    = (float*)d_out;
    float* latent = out;
    float* fr0    = out + BATCH * D_LAT;
    float* fr1    = fr0 + BATCH * H1N;

    char* p = (char*)d_ws;
    float*     H_c = (float*)p;               p += (size_t)MC * H1N * 4;   // 52.4 MB (reused for H1 & H2)
    _Float16*  Xh  = (_Float16*)p;            p += (size_t)MC * D_IN * 2;  // 13.1 MB
    _Float16*  Xl  = (_Float16*)p;            p += (size_t)MC * D_IN * 2;
    _Float16*  S0  = (_Float16*)p;            p += (size_t)MC * H1N * 2;   // 26.2 MB
    _Float16*  W1h = (_Float16*)p;            p += (size_t)H1N * D_IN * 2;
    _Float16*  W1l = (_Float16*)p;            p += (size_t)H1N * D_IN * 2;
    _Float16*  W2h = (_Float16*)p;            p += (size_t)H2N * H1N * 2;
    _Float16*  W2l = (_Float16*)p;            p += (size_t)H2N * H1N * 2;
    float*     m0s = (float*)p;               p += (size_t)BHE * 4;
    float*     c0s = (float*)p;               p += (size_t)BHE * 4;
    float*     m1s = (float*)p;               p += (size_t)BHE * 4;
    float*     c1s = (float*)p;               p += (size_t)BHE * 4;
    unsigned char* s1l = (unsigned char*)p;   p += (size_t)BHE;

    // weight splits (once)
    split_kern<<<dim3((H1N * D_IN / 4 + 255) / 256), 256, 0, stream>>>(W1, W1h, W1l, H1N * D_IN / 4);
    split_kern<<<dim3((H2N * H1N / 4 + 255) / 256), 256, 0, stream>>>(W2, W2h, W2l, H2N * H1N / 4);

    for (int c = 0; c < NCH; ++c) {
        const float* Xc = X + (size_t)c * TC * BATCH * D_IN;
        const int first = (c == 0), last = (c == NCH - 1);
        split_kern<<<dim3((MC * D_IN / 4 + 255) / 256), 256, 0, stream>>>(Xc, Xh, Xl, MC * D_IN / 4);
        gemm_mfma<true><<<dim3(MC / 128, H1N / 128), 256, 0, stream>>>(
            Xh, Xl, W1h, W1l, b1, H_c, MC, H1N, D_IN);
        lif_scan_c<<<dim3(BHE / 256), 256, 0, stream>>>(
            H_c, beta0, S0, m0s, c0s, fr0, nullptr, first, last, 1, 0);
        gemm_mfma<false><<<dim3(MC / 128, H2N / 128), 256, 0, stream>>>(
            S0, nullptr, W2h, W2l, b2, H_c, MC, H2N, H1N);
        lif_scan_c<<<dim3(BHE / 256), 256, 0, stream>>>(
            H_c, beta1, nullptr, m1s, c1s, fr1, s1l, first, last, 0, 1);
    }
    latent_ln<<<dim3(BATCH), 128, 0, stream>>>(s1l, Wout, bout, lng, lnb, latent);
}